// Round 2
// baseline (32.552 us; speedup 1.0000x reference)
//
#include <hip/hip_runtime.h>
#include <math.h>

// Problem constants (from reference):
//   N=4096, P=4  -> B = 16384 rows, processed 2 rows per block (8192 blocks)
//   SMK = 567 (signal length), L = 8 (taps), OUTLEN = SMK+L-1 = 574
//   M = 64 (DFT size)
// Output layout (flat, concatenated in return order):
//   out:    (B, 574, 2) float32   = 18,808,832 elems
//   H_true: (B,  64, 2) float32   =  2,097,152 elems
//
// Alignment facts enabling full float4 (16B/lane) traffic with 2 rows/block:
//   x   row pair: 2*567*8  = 9072 B  = 567 float4, base 9072*bid (16B aligned)
//   out row pair: 2*574*8  = 9184 B  = 574 float4, base 9184*bid (16B aligned)
//   H   row pair: 2*64*8   = 1024 B  =  64 float4
//   cof row pair: 2*8*8    =  128 B  =   8 float4

#define B_ROWS 16384
#define SMK    567
#define LTAPS  8
#define OUTLEN 574
#define MFFT   64
#define PADS   (LTAPS - 1)          // 7
#define XSLEN  (SMK + 2 * PADS)     // 581

__global__ __launch_bounds__(256) void channel_kernel(
    const float4* __restrict__ x4,    // (B/2 blocks) x as float4
    const float4* __restrict__ cof4,  // cof as float4
    float4* __restrict__ out4,        // out as float4
    float4* __restrict__ H4)          // H as float4
{
    __shared__ float2 xs[2][XSLEN];   // padded signal, both rows (~9.3 KB)
    __shared__ float2 ht[2][LTAPS];   // taps, both rows

    const int bid = blockIdx.x;       // row pair index; rows 2*bid, 2*bid+1
    const int tid = threadIdx.x;

    // --- zero the 2x14 pad slots ---
    if (tid < 2 * 2 * PADS) {         // 28 threads
        int r = tid / (2 * PADS);
        int p = tid % (2 * PADS);
        int idx = (p < PADS) ? p : (SMK + p);   // [0..6] and [574..580]
        xs[r][idx] = make_float2(0.0f, 0.0f);
    }

    // --- stage x: 567 aligned float4 loads cover both rows ---
    const float4* __restrict__ xg = x4 + (size_t)bid * SMK;
    for (int t = tid; t < SMK; t += 256) {
        float4 v = xg[t];
        int e0 = 2 * t;               // complex element index within the pair
        int e1 = 2 * t + 1;
        if (e0 < SMK) xs[0][e0 + PADS]       = make_float2(v.x, v.y);
        else          xs[1][e0 - SMK + PADS] = make_float2(v.x, v.y);
        if (e1 < SMK) xs[0][e1 + PADS]       = make_float2(v.z, v.w);
        else          xs[1][e1 - SMK + PADS] = make_float2(v.z, v.w);
    }

    // --- stage taps: 8 aligned float4 loads ---
    if (tid < 8) {
        float4 v = cof4[(size_t)bid * 8 + tid];
        float2* hf = &ht[0][0];
        hf[2 * tid]     = make_float2(v.x, v.y);
        hf[2 * tid + 1] = make_float2(v.z, v.w);
    }

    __syncthreads();

    // --- FIR: 574 float4 outputs per block (2 complex outputs per thread-iter) ---
    float4* __restrict__ og = out4 + (size_t)bid * OUTLEN;  // 574 float4
    #pragma unroll
    for (int it = 0; it < 3; ++it) {
        int v = tid + it * 256;
        if (v < OUTLEN) {
            int r   = (v >= OUTLEN / 2) ? 1 : 0;     // 287 float4 per row
            int idx = v - r * (OUTLEN / 2);
            const float2* __restrict__ hs = ht[r];
            const float2* __restrict__ xr = xs[r];
            int i0 = 2 * idx;                         // first complex output
            float sr0 = 0.f, si0 = 0.f, sr1 = 0.f, si1 = 0.f;
            #pragma unroll
            for (int j = 0; j < LTAPS; ++j) {
                float2 hj = hs[j];
                float2 a  = xr[i0 - j + PADS];        // for output i0
                float2 c  = xr[i0 + 1 - j + PADS];    // for output i0+1 (CSEs with a)
                sr0 = fmaf(hj.x, a.x, sr0); sr0 = fmaf(-hj.y, a.y, sr0);
                si0 = fmaf(hj.x, a.y, si0); si0 = fmaf(hj.y, a.x, si0);
                sr1 = fmaf(hj.x, c.x, sr1); sr1 = fmaf(-hj.y, c.y, sr1);
                si1 = fmaf(hj.x, c.y, si1); si1 = fmaf(hj.y, c.x, si1);
            }
            og[v] = make_float4(sr0, si0, sr1, si1);
        }
    }

    // --- 64-point DFT of 8 taps: 64 float4 per block (2 k's per thread) ---
    if (tid < MFFT) {
        int r  = tid >> 5;            // row within pair
        int kp = tid & 31;            // float4 index within row (k = 2kp, 2kp+1)
        const float2* __restrict__ hs = ht[r];
        float ar0 = 0.f, ai0 = 0.f, ar1 = 0.f, ai1 = 0.f;
        int k0 = 2 * kp, k1 = 2 * kp + 1;
        #pragma unroll
        for (int l = 0; l < LTAPS; ++l) {
            float2 hl = hs[l];
            int t0 = (k0 * l) & (MFFT - 1);
            int t1 = (k1 * l) & (MFFT - 1);
            float s0, c0, s1, c1;
            __sincosf(-6.2831853071795864769f * (float)t0 * (1.0f / (float)MFFT), &s0, &c0);
            __sincosf(-6.2831853071795864769f * (float)t1 * (1.0f / (float)MFFT), &s1, &c1);
            ar0 = fmaf(hl.x, c0, ar0); ar0 = fmaf(-hl.y, s0, ar0);
            ai0 = fmaf(hl.x, s0, ai0); ai0 = fmaf(hl.y, c0, ai0);
            ar1 = fmaf(hl.x, c1, ar1); ar1 = fmaf(-hl.y, s1, ar1);
            ai1 = fmaf(hl.x, s1, ai1); ai1 = fmaf(hl.y, c1, ai1);
        }
        H4[(size_t)bid * MFFT + tid] = make_float4(ar0, ai0, ar1, ai1);
    }
}

extern "C" void kernel_launch(void* const* d_in, const int* in_sizes, int n_in,
                              void* d_out, int out_size, void* d_ws, size_t ws_size,
                              hipStream_t stream) {
    const float4* x4   = (const float4*)d_in[0];  // (N,P,SMK,2) f32
    const float4* cof4 = (const float4*)d_in[1];  // (N,P,L,2)  f32
    float* outf = (float*)d_out;

    float4* out4 = (float4*)outf;                                    // (B,574) complex
    float4* H4   = (float4*)(outf + (size_t)B_ROWS * OUTLEN * 2);    // (B,64) complex

    channel_kernel<<<B_ROWS / 2, 256, 0, stream>>>(x4, cof4, out4, H4);
}

// Round 3
// 32.552 us; speedup vs baseline: 1.0000x; 1.0000x over previous
//
#include <hip/hip_runtime.h>

// Problem constants:
//   N=4096, P=4 -> B = 16384 rows; 2 rows per block -> 8192 blocks
//   SMK = 567, L = 8 taps, OUTLEN = 574, M = 64 (DFT)
// Output layout (flat): out (B,574,2) f32 then H (B,64,2) f32.
//
// All global traffic is aligned float4 (16B/lane):
//   x   row pair = 567 float4;  out row pair = 574 float4
//   cof row pair = 8 float4;    H   row pair = 64 float4
// All LDS traffic is conflict-free:
//   signal staged SoA (xr[], xi[]) with even row stride 582
//   (8 head pads + 567 + 7 tail pads); FIR reads are aligned
//   ds_read_b64 at 8B lane-stride; staging writes are b32 at 8B stride.

#define B_ROWS  16384
#define SMK     567
#define LTAPS   8
#define OUTLEN  574
#define MFFT    64
#define HPAD    8
#define RSTRIDE 582   // HPAD + SMK + 7, even

__global__ __launch_bounds__(256) void channel_kernel(
    const float4* __restrict__ x4,    // x as float4 (2 rows = 567 per block)
    const float4* __restrict__ cof4,  // cof as float4 (8 per block)
    float4* __restrict__ out4,        // out as float4 (574 per block)
    float4* __restrict__ H4)          // H as float4 (64 per block)
{
    __shared__ float  xr[2 * RSTRIDE];   // real part, padded, both rows
    __shared__ float  xi[2 * RSTRIDE];   // imag part
    __shared__ float2 ht[2][LTAPS];      // taps

    const int bid = blockIdx.x;
    const int tid = threadIdx.x;

    // --- zero the pad slots: per row, head [0..7] and tail [575..581] ---
    if (tid < 30) {
        int r = tid / 15, p = tid % 15;
        int idx = r * RSTRIDE + (p < HPAD ? p : p + SMK);  // 575..581 for p>=8
        xr[idx] = 0.0f;
        xi[idx] = 0.0f;
    }

    // --- stage x: 567 aligned float4 loads cover both rows ---
    // concat element e (0..1133): row r = e>=567, f(e) = e + HPAD + 15*r
    const float4* __restrict__ xg = x4 + (size_t)bid * SMK;
    for (int t = tid; t < SMK; t += 256) {
        float4 v = xg[t];
        int e0 = 2 * t, e1 = 2 * t + 1;
        int f0 = e0 + HPAD + ((e0 >= SMK) ? (RSTRIDE - SMK) : 0);
        int f1 = e1 + HPAD + ((e1 >= SMK) ? (RSTRIDE - SMK) : 0);
        xr[f0] = v.x; xi[f0] = v.y;
        xr[f1] = v.z; xi[f1] = v.w;
    }

    // --- stage taps: 8 aligned float4 loads ---
    if (tid < 8) {
        float4 v = cof4[(size_t)bid * 8 + tid];
        float2* hf = &ht[0][0];
        hf[2 * tid]     = make_float2(v.x, v.y);
        hf[2 * tid + 1] = make_float2(v.z, v.w);
    }

    __syncthreads();

    // --- FIR: 574 float4 outputs per block (2 complex outputs per v) ---
    float4* __restrict__ og = out4 + (size_t)bid * OUTLEN;
    #pragma unroll
    for (int k = 0; k < 3; ++k) {
        int v = tid + k * 256;
        if (v < OUTLEN) {
            int r  = (v >= OUTLEN / 2) ? 1 : 0;   // 287 float4 per row
            int p  = v - r * (OUTLEN / 2);
            int i0 = 2 * p;                        // first complex output idx
            int base = r * RSTRIDE + i0;           // float idx of s = i0-8 (even)
            // window w[m] = x[s = i0-8+m], m=0..9 ; 5 aligned float2 reads each
            float wr[10], wi[10];
            #pragma unroll
            for (int c = 0; c < 5; ++c) {
                float2 a = *(const float2*)&xr[base + 2 * c];
                float2 b = *(const float2*)&xi[base + 2 * c];
                wr[2 * c] = a.x; wr[2 * c + 1] = a.y;
                wi[2 * c] = b.x; wi[2 * c + 1] = b.y;
            }
            float sr0 = 0.f, si0 = 0.f, sr1 = 0.f, si1 = 0.f;
            #pragma unroll
            for (int j = 0; j < LTAPS; ++j) {
                float2 h = ht[r][j];
                float ar = wr[8 - j], ai = wi[8 - j];  // out i0  : s = i0-j
                float br = wr[9 - j], bi = wi[9 - j];  // out i0+1: s = i0+1-j
                sr0 = fmaf(h.x, ar, sr0); sr0 = fmaf(-h.y, ai, sr0);
                si0 = fmaf(h.x, ai, si0); si0 = fmaf(h.y, ar, si0);
                sr1 = fmaf(h.x, br, sr1); sr1 = fmaf(-h.y, bi, sr1);
                si1 = fmaf(h.x, bi, si1); si1 = fmaf(h.y, br, si1);
            }
            og[v] = make_float4(sr0, si0, sr1, si1);
        }
    }

    // --- 64-point DFT of 8 taps: 64 float4 per block (2 k's per thread) ---
    if (tid < MFFT) {
        int r  = tid >> 5;            // row within pair
        int kp = tid & 31;            // float4 index within row
        const float2* __restrict__ hs = ht[r];
        float ar0 = 0.f, ai0 = 0.f, ar1 = 0.f, ai1 = 0.f;
        int k0 = 2 * kp, k1 = 2 * kp + 1;
        #pragma unroll
        for (int l = 0; l < LTAPS; ++l) {
            float2 hl = hs[l];
            int t0 = (k0 * l) & (MFFT - 1);
            int t1 = (k1 * l) & (MFFT - 1);
            float s0, c0, s1, c1;
            __sincosf(-6.2831853071795864769f * (float)t0 * (1.0f / (float)MFFT), &s0, &c0);
            __sincosf(-6.2831853071795864769f * (float)t1 * (1.0f / (float)MFFT), &s1, &c1);
            ar0 = fmaf(hl.x, c0, ar0); ar0 = fmaf(-hl.y, s0, ar0);
            ai0 = fmaf(hl.x, s0, ai0); ai0 = fmaf(hl.y, c0, ai0);
            ar1 = fmaf(hl.x, c1, ar1); ar1 = fmaf(-hl.y, s1, ar1);
            ai1 = fmaf(hl.x, s1, ai1); ai1 = fmaf(hl.y, c1, ai1);
        }
        H4[(size_t)bid * MFFT + tid] = make_float4(ar0, ai0, ar1, ai1);
    }
}

extern "C" void kernel_launch(void* const* d_in, const int* in_sizes, int n_in,
                              void* d_out, int out_size, void* d_ws, size_t ws_size,
                              hipStream_t stream) {
    const float4* x4   = (const float4*)d_in[0];  // (N,P,SMK,2) f32
    const float4* cof4 = (const float4*)d_in[1];  // (N,P,L,2)  f32
    float* outf = (float*)d_out;

    float4* out4 = (float4*)outf;                                  // (B,574) complex
    float4* H4   = (float4*)(outf + (size_t)B_ROWS * OUTLEN * 2);  // (B,64) complex

    channel_kernel<<<B_ROWS / 2, 256, 0, stream>>>(x4, cof4, out4, H4);
}